// Round 1
// baseline (597.702 us; speedup 1.0000x reference)
//
#include <hip/hip_runtime.h>
#include <math.h>

#define Bb 128
#define Tt 1024
#define Ll 96

typedef float v2f __attribute__((ext_vector_type(2)));
typedef float v4f __attribute__((ext_vector_type(4)));

// One block = one batch = ONE wave (64 lanes). Lane i owns states m=2i,2i+1
// (i<48; lanes 48-63 compute garbage on clamped addresses, never stored).
//
// Linear-space recurrence (log/exp moved OFF the serial critical path):
//   q_t = (E^T q_{t-1}) * exp(x_t) * 2^{-k_{t-1}},  E = exp(trans)
//   k_t = floor(log2 q_t[0])  (exponent bits via readfirstlane -> SALU)
//   true state_t = log q_t + D_t,  D_t = D_{t-1} + k_{t-1}*ln2  (Dk integer: EXACT)
// Per-step critical path: ds_write_b64 -> 24x broadcast ds_read_b128 ->
// 96x v_pk_fma_f32 -> 1 pk-mul -> ds_write. No barrier, no log/exp on path.
__global__ __launch_bounds__(64, 1) void crf_fwd_kernel(
    const float* __restrict__ inputs,      // (B, T, L) fp32
    const int*   __restrict__ labels_idx,  // (B, T) int32
    const float* __restrict__ trans,       // (L, L) fp32
    float*       __restrict__ out)         // (B, 1) fp32
{
    const int b   = blockIdx.x;
    const int i   = threadIdx.x;                    // 0..63
    const int col = (2 * i < Ll) ? 2 * i : (Ll - 2); // clamp lanes 48..63

    __shared__ __align__(16) float pbuf[2][Ll];     // double-buffered q

    const float* xbase = inputs + (size_t)b * Tt * Ll;

    // ---- E in registers, paired over l for clean pk-FMA operands ----
    // El0[p] = {E[2p][col],   E[2p+1][col]}   (output m = col)
    // El1[p] = {E[2p][col+1], E[2p+1][col+1]} (output m = col+1)
    v2f El0[Ll / 2], El1[Ll / 2];
    #pragma unroll
    for (int p = 0; p < Ll / 2; ++p) {
        v2f r0 = *reinterpret_cast<const v2f*>(&trans[(2 * p)     * Ll + col]);
        v2f r1 = *reinterpret_cast<const v2f*>(&trans[(2 * p + 1) * Ll + col]);
        El0[p] = (v2f){__expf(r0.x), __expf(r1.x)};
        El1[p] = (v2f){__expf(r0.y), __expf(r1.y)};
    }

    // ---- point_score + trans_score (independent of the scan) ----
    float ps = 0.f;
    {
        const int* lb = labels_idx + b * Tt;
        #pragma unroll 4
        for (int t = i; t < Tt; t += 64) {
            int i0 = lb[t];
            ps += xbase[t * Ll + i0];
            if (t < Tt - 1) ps += trans[i0 * Ll + lb[t + 1]];
        }
        #pragma unroll
        for (int off = 32; off; off >>= 1) ps += __shfl_xor(ps, off, 64);
    }

    // ---- q_0 = exp(x_0); seed normalizer from its exponent field ----
    v2f x0 = *reinterpret_cast<const v2f*>(&xbase[col]);
    v2f qv = (v2f){__expf(x0.x), __expf(x0.y)};
    if (i < 48) *reinterpret_cast<v2f*>(&pbuf[0][2 * i]) = qv;
    unsigned gb = (unsigned)__builtin_amdgcn_readfirstlane((int)__float_as_uint(qv.x));
    int   kcur = (int)((gb >> 23) & 0xffu) - 127;              // floor(log2 q[0])
    float r    = __uint_as_float((unsigned)(127 - kcur) << 23); // exact 2^-k
    int   Dk   = 0;

    // ---- x prefetch (depth 2) + exp(x) pipelined one step ahead ----
    v2f xr1 = *reinterpret_cast<const v2f*>(&xbase[1 * Ll + col]);
    v2f exw = (v2f){__expf(xr1.x), __expf(xr1.y)};  // exp(x_1)
    v2f xa  = *reinterpret_cast<const v2f*>(&xbase[2 * Ll + col]);
    v2f xb  = *reinterpret_cast<const v2f*>(&xbase[3 * Ll + col]);

    for (int t = 1; t < Tt; ++t) {
        const int wp = t & 1, rp = wp ^ 1;

        Dk += kcur;              // D_t += k_{t-1} (integer, exact)
        v2f w = exw * r;         // exp(x_t) * 2^-k : off-path, ready before FMAs end

        // ---- matvec: 24 broadcast b128 reads, 96 pk-FMAs ----
        const v4f* qb = reinterpret_cast<const v4f*>(&pbuf[rp][0]);
        v2f a00 = {0.f, 0.f}, a01 = {0.f, 0.f}, a10 = {0.f, 0.f}, a11 = {0.f, 0.f};
        #pragma unroll
        for (int j = 0; j < Ll / 8; ++j) {          // 12 iters x 2 v4f
            v4f qA = qb[2 * j];
            v4f qB = qb[2 * j + 1];
            v2f qAlo = {qA.x, qA.y}, qAhi = {qA.z, qA.w};
            v2f qBlo = {qB.x, qB.y}, qBhi = {qB.z, qB.w};
            a00 += qAlo * El0[4 * j + 0];  a10 += qAlo * El1[4 * j + 0];
            a01 += qAhi * El0[4 * j + 1];  a11 += qAhi * El1[4 * j + 1];
            a00 += qBlo * El0[4 * j + 2];  a10 += qBlo * El1[4 * j + 2];
            a01 += qBhi * El0[4 * j + 3];  a11 += qBhi * El1[4 * j + 3];
        }
        v2f sA = a00 + a01;
        v2f sB = a10 + a11;
        qv = (v2f){sA.x + sA.y, sB.x + sB.y} * w;

        if (i < 48) *reinterpret_cast<v2f*>(&pbuf[wp][2 * i]) = qv;
        // same-wave DS ops are in-order; drain lgkm as cheap insurance, keep
        // vmcnt untouched so x-prefetch loads stay in flight across steps.
        asm volatile("s_waitcnt lgkmcnt(0)" ::: "memory");

        // ---- off-path bookkeeping for step t+1 (SALU + 2 transcendentals) ----
        gb   = (unsigned)__builtin_amdgcn_readfirstlane((int)__float_as_uint(qv.x));
        kcur = (int)((gb >> 23) & 0xffu) - 127;
        r    = __uint_as_float((unsigned)(127 - kcur) << 23);

        exw = (v2f){__expf(xa.x), __expf(xa.y)};    // exp(x_{t+1})
        xa  = xb;
        int row = t + 3; if (row > Tt - 1) row = Tt - 1;
        xb  = *reinterpret_cast<const v2f*>(&xbase[row * Ll + col]);
    }

    // ---- log_norm = Dk*ln2 + log(sum_m q_T[m]); out = log_norm - scores ----
    float s = (i < 48) ? (qv.x + qv.y) : 0.f;
    #pragma unroll
    for (int off = 32; off; off >>= 1) s += __shfl_xor(s, off, 64);
    if (i == 0) {
        double ln = (double)Dk * 0.6931471805599453 + log((double)s);
        out[b] = (float)(ln - (double)ps);
    }
}

extern "C" void kernel_launch(void* const* d_in, const int* in_sizes, int n_in,
                              void* d_out, int out_size, void* d_ws, size_t ws_size,
                              hipStream_t stream) {
    const float* inputs     = (const float*)d_in[0];
    const int*   labels_idx = (const int*)d_in[1];
    const float* trans      = (const float*)d_in[2];
    float*       out        = (float*)d_out;

    crf_fwd_kernel<<<dim3(Bb), dim3(64), 0, stream>>>(inputs, labels_idx, trans, out);
}